// Round 1
// baseline (796.432 us; speedup 1.0000x reference)
//
#include <hip/hip_runtime.h>
#include <hip/hip_bf16.h>
#include <stdint.h>

typedef __hip_bfloat16 bf16;
typedef __attribute__((ext_vector_type(8))) __bf16 bf16x8;
typedef __attribute__((ext_vector_type(8))) unsigned short ushort8;
typedef __attribute__((ext_vector_type(4))) float floatx4;

#define MFMA_16x16x32(a, b, c) __builtin_amdgcn_mfma_f32_16x16x32_bf16((a), (b), (c), 0, 0, 0)

// async global->LDS, 16B per lane. LDS dest = wave-uniform base + lane*16.
__device__ __forceinline__ void async_load16(const bf16* g, bf16* l) {
  __builtin_amdgcn_global_load_lds(
      (const __attribute__((address_space(1))) unsigned int*)g,
      (__attribute__((address_space(3))) unsigned int*)l,
      16, 0, 0);
}

// DPP cross-lane (VALU pipe, not LDS): 16-lane row reductions
template <int CTRL>
__device__ __forceinline__ float dpp_f(float x) {
  return __builtin_bit_cast(float, __builtin_amdgcn_update_dpp(
      0, __builtin_bit_cast(int, x), CTRL, 0xf, 0xf, true));
}
__device__ __forceinline__ float row_max16(float x) {
  x = fmaxf(x, dpp_f<0xB1>(x));   // quad_perm(1,0,3,2)
  x = fmaxf(x, dpp_f<0x4E>(x));   // quad_perm(2,3,0,1)
  x = fmaxf(x, dpp_f<0x124>(x));  // row_ror:4
  x = fmaxf(x, dpp_f<0x128>(x));  // row_ror:8
  return x;
}
__device__ __forceinline__ float row_sum16(float x) {
  x += dpp_f<0xB1>(x);
  x += dpp_f<0x4E>(x);
  x += dpp_f<0x124>(x);
  x += dpp_f<0x128>(x);
  return x;
}

// ---------------------------------------------------------------------------
// fp32 -> bf16 cast, 8 elems/thread
// ---------------------------------------------------------------------------
__global__ __launch_bounds__(256)
void f32_to_bf16_k(const float* __restrict__ in, bf16* __restrict__ out, int n)
{
  const int i = (blockIdx.x * 256 + threadIdx.x) * 8;
  if (i >= n) return;
  bf16 tmp[8];
#pragma unroll
  for (int j = 0; j < 8; ++j) tmp[j] = __float2bfloat16(in[i + j]);
  *(ushort8*)&out[i] = *(const ushort8*)tmp;
}

// ---------------------------------------------------------------------------
// C[M,N] = A[M,K] @ B[N,K]^T  — m97 tile + XOR swizzle + issue-after-barrier
// double-buffer: at __syncthreads the outstanding loads are one full compute
// phase old, so the vmcnt(0) drain is free. One barrier per K-step.
// ---------------------------------------------------------------------------
__global__ __launch_bounds__(256, 2)
void gemm_bt(const bf16* __restrict__ A, const bf16* __restrict__ B,
             bf16* __restrict__ Cb, float* __restrict__ Cf,
             int M, int N, int K)
{
  __shared__ __align__(16) bf16 sA[2][128 * 32];
  __shared__ __align__(16) bf16 sB[2][128 * 32];

  const int tid  = threadIdx.x;
  const int lane = tid & 63;
  const int w    = tid >> 6;
  const int wm   = w >> 1;
  const int wn   = w & 1;
  const int quad = lane >> 4;
  const int l16  = lane & 15;
  const int tileM = blockIdx.y * 128;
  const int tileN = blockIdx.x * 128;
  const int rmask = (l16 & 3) ^ ((l16 >> 2) & 3);

  floatx4 acc[4][4];
#pragma unroll
  for (int i = 0; i < 4; ++i)
#pragma unroll
    for (int j = 0; j < 4; ++j) acc[i][j] = (floatx4){0.f, 0.f, 0.f, 0.f};

  int st_row[2], st_col[2];
#pragma unroll
  for (int s = 0; s < 2; ++s) {
    const int cid = (w * 2 + s) * 64 + lane;
    const int row = cid >> 2;
    st_row[s] = row;
    st_col[s] = ((cid & 3) ^ ((row & 3) ^ ((row >> 2) & 3))) << 3;
  }

  // prologue: stage k0=0 into buf 0
#pragma unroll
  for (int s = 0; s < 2; ++s) {
    async_load16(A + (size_t)(tileM + st_row[s]) * K + st_col[s], &sA[0][(w * 2 + s) * 512]);
    async_load16(B + (size_t)(tileN + st_row[s]) * K + st_col[s], &sB[0][(w * 2 + s) * 512]);
  }

  int p = 0;
  for (int k0 = 0; k0 < K; k0 += 32, p ^= 1) {
    __syncthreads();  // drains loads(k0) (issued last iter) — latency hidden
    if (k0 + 32 < K) {
#pragma unroll
      for (int s = 0; s < 2; ++s) {
        async_load16(A + (size_t)(tileM + st_row[s]) * K + (k0 + 32) + st_col[s], &sA[p ^ 1][(w * 2 + s) * 512]);
        async_load16(B + (size_t)(tileN + st_row[s]) * K + (k0 + 32) + st_col[s], &sB[p ^ 1][(w * 2 + s) * 512]);
      }
    }

    bf16x8 af[4], bfr[4];
#pragma unroll
    for (int i = 0; i < 4; ++i)
      af[i] = *(const bf16x8*)&sA[p][(wm * 64 + i * 16 + l16) * 32 + (quad ^ rmask) * 8];
#pragma unroll
    for (int j = 0; j < 4; ++j)
      bfr[j] = *(const bf16x8*)&sB[p][(wn * 64 + j * 16 + l16) * 32 + (quad ^ rmask) * 8];
    __builtin_amdgcn_s_setprio(1);
#pragma unroll
    for (int i = 0; i < 4; ++i)
#pragma unroll
      for (int j = 0; j < 4; ++j)
        acc[i][j] = MFMA_16x16x32(af[i], bfr[j], acc[i][j]);
    __builtin_amdgcn_s_setprio(0);
  }

#pragma unroll
  for (int i = 0; i < 4; ++i)
#pragma unroll
    for (int j = 0; j < 4; ++j)
#pragma unroll
      for (int r = 0; r < 4; ++r) {
        const int row = tileM + wm * 64 + i * 16 + quad * 4 + r;
        const int col = tileN + wn * 64 + j * 16 + l16;
        if (Cf) Cf[(size_t)row * N + col] = acc[i][j][r];
        else    Cb[(size_t)row * N + col] = __float2bfloat16(acc[i][j][r]);
      }
}

// ---------------------------------------------------------------------------
// V transpose: qkv[b*T+t, 4096 + h*128 + dim] -> Vt[(bh*128 + dim)*2048 + t]
// ---------------------------------------------------------------------------
__global__ __launch_bounds__(256)
void transpose_v(const bf16* __restrict__ qkv, bf16* __restrict__ Vt)
{
  __shared__ bf16 tile[64 * 128];
  const int t0 = blockIdx.x * 64;
  const int bh = blockIdx.y;
  const int b = bh >> 4;
  const int h = bh & 15;
  const int tid = threadIdx.x;
  const bf16* src = qkv + (size_t)(b * 2048 + t0) * 6144 + 4096 + h * 128;
#pragma unroll
  for (int s = 0; s < 4; ++s) {
    const int cid = s * 256 + tid;
    const int row = cid >> 4;
    const int col = (cid & 15) << 3;
    *(ushort8*)&tile[row * 128 + col] = *(const ushort8*)&src[(size_t)row * 6144 + col];
  }
  __syncthreads();
  const int dim = tid >> 1;
  const int tp  = (tid & 1) << 5;
  bf16 vals[32];
#pragma unroll
  for (int t = 0; t < 32; ++t) vals[t] = tile[(tp + t) * 128 + dim];
  bf16* dst = Vt + (size_t)(bh * 128 + dim) * 2048 + t0 + tp;
#pragma unroll
  for (int s = 0; s < 4; ++s) *(ushort8*)&dst[s * 8] = ((const ushort8*)vals)[s];
}

// ---------------------------------------------------------------------------
// Flash attention, causal. BQ=128, BKV=32, double-buffered K/V, pipelined.
// 4 waves; wave w owns q-rows w*32..w*32+31 (2 m-subtiles). Q in registers.
// Softmax: lazy per-thread denominator (row_sum16 only in epilogue) +
// defer-max (T13): skip row_max16/alpha/O-rescale unless some row's max grew
// by > THR (log2 units). P bounded by 2^THR. LDS 42KB -> 3 blocks/CU.
// ---------------------------------------------------------------------------
__global__ __launch_bounds__(256, 2)
void flash_attn(const bf16* __restrict__ qkv, const bf16* __restrict__ Vt,
                bf16* __restrict__ outb)
{
  // buf p (8192 elems): sK [32 keys][128 d] at +0, sV [128 d][32 keys] at +4096
  // Q (128x128 = 16384 elems) staged once through both bufs. sP after.
  __shared__ __align__(16) bf16 smem[16384 + 4 * 32 * 40];
  bf16* sP = smem + 16384;

  const int qb  = gridDim.x - 1 - blockIdx.x;
  const int bh  = blockIdx.y;
  const int b   = bh >> 4;
  const int h   = bh & 15;
  const int tid = threadIdx.x;
  const int lane = tid & 63;
  const int w    = tid >> 6;
  const int quad = lane >> 4;
  const int l16  = lane & 15;

  const size_t rs = 6144;
  const bf16* Qg = qkv + (size_t)(b * 2048 + qb * 128) * rs + h * 128;
  const bf16* Kg = qkv + (size_t)(b * 2048) * rs + 2048 + h * 128;
  const bf16* Vg = Vt + (size_t)bh * 128 * 2048;

  // ---- stage Q (128x128), swizzled 16-chunk rows ----
#pragma unroll
  for (int s = 0; s < 8; ++s) {
    const int cid = (w * 8 + s) * 64 + lane;
    const int row = cid >> 4;
    const int col = ((cid & 15) ^ (row & 15)) << 3;
    async_load16(Qg + (size_t)row * rs + col, &smem[(w * 8 + s) * 512]);
  }
  __syncthreads();

  bf16x8 qf[2][4];
#pragma unroll
  for (int i = 0; i < 2; ++i)
#pragma unroll
    for (int kc = 0; kc < 4; ++kc)
      qf[i][kc] = *(const bf16x8*)&smem[(w * 32 + i * 16 + l16) * 128 + (((kc * 4 + quad) ^ l16) << 3)];
  __syncthreads();  // all waves done reading Q before buf0 is overwritten

  // K/V staging index precompute (2 insts each per wave per tile)
  int kq_row[2], kq_col[2], vv_row[2], vv_col[2];
#pragma unroll
  for (int s = 0; s < 2; ++s) {
    const int cid = (w * 2 + s) * 64 + lane;
    kq_row[s] = cid >> 4;                               // 16 chunks per 128-d row
    kq_col[s] = ((cid & 15) ^ (kq_row[s] & 15)) << 3;
    vv_row[s] = cid >> 2;                               // 4 chunks per 32-key row
    vv_col[s] = ((cid & 3) ^ (vv_row[s] & 3)) << 3;
  }

  const int kb_end = 4 * qb + 4;
  // prologue: stage tile 0 into buf 0
#pragma unroll
  for (int s = 0; s < 2; ++s) {
    async_load16(Kg + (size_t)kq_row[s] * rs + kq_col[s],      &smem[(w * 2 + s) * 512]);
    async_load16(Vg + (size_t)vv_row[s] * 2048 + vv_col[s],    &smem[4096 + (w * 2 + s) * 512]);
  }

  floatx4 o[2][8];
#pragma unroll
  for (int i = 0; i < 2; ++i)
#pragma unroll
    for (int s = 0; s < 8; ++s) o[i][s] = (floatx4){0.f, 0.f, 0.f, 0.f};
  // m_i: running row max (log2 units). thr = m_i + THR (defer-max trigger).
  // lp: per-THREAD partial denominator; row-reduced once in the epilogue.
  float m_i[2][4], thr[2][4], lp[2][4];
#pragma unroll
  for (int i = 0; i < 2; ++i)
#pragma unroll
    for (int r = 0; r < 4; ++r) {
      m_i[i][r] = -__builtin_inff();
      thr[i][r] = -__builtin_inff();
      lp[i][r]  = 0.f;
    }

  const float csc = 1.4426950408889634f * 0.08838834764831845f; // log2(e)/sqrt(128)
  const float THR = 8.0f;  // P bounded by 2^8 = 256

  for (int kb = 0; kb < kb_end; ++kb) {
    __syncthreads();  // drains loads(kb) (issued last iter) + protects bufs
    if (kb + 1 < kb_end) {
      bf16* nb = smem + ((kb + 1) & 1) * 8192;
#pragma unroll
      for (int s = 0; s < 2; ++s) {
        async_load16(Kg + (size_t)((kb + 1) * 32 + kq_row[s]) * rs + kq_col[s], nb + (w * 2 + s) * 512);
        async_load16(Vg + (size_t)vv_row[s] * 2048 + (kb + 1) * 32 + vv_col[s], nb + 4096 + (w * 2 + s) * 512);
      }
    }
    // wave-uniform skip: whole key tile above all of this wave's rows
    if (kb * 32 > qb * 128 + w * 32 + 31) continue;

    const bf16* sK = smem + (kb & 1) * 8192;
    const bf16* sV = sK + 4096;

    // S = Q_w(32x128) @ K^T(128x32)
    floatx4 sacc[2][2];
#pragma unroll
    for (int i = 0; i < 2; ++i)
#pragma unroll
      for (int j = 0; j < 2; ++j) sacc[i][j] = (floatx4){0.f, 0.f, 0.f, 0.f};
    __builtin_amdgcn_s_setprio(1);
#pragma unroll
    for (int kc = 0; kc < 4; ++kc) {
      const int ch = ((kc * 4 + quad) ^ l16) << 3;
#pragma unroll
      for (int j = 0; j < 2; ++j) {
        const bf16x8 bk = *(const bf16x8*)&sK[(j * 16 + l16) * 128 + ch];
        sacc[0][j] = MFMA_16x16x32(qf[0][kc], bk, sacc[0][j]);
        sacc[1][j] = MFMA_16x16x32(qf[1][kc], bk, sacc[1][j]);
      }
    }
    __builtin_amdgcn_s_setprio(0);

    // scale + causal mask; masked -> -inf (exp2(-inf)=0, -inf never > thr)
    const bool diag = (kb * 32 + 31 > qb * 128 + w * 32);
    float p[2][2][4];
    bool need = false;
#pragma unroll
    for (int i = 0; i < 2; ++i) {
      const int qrow = qb * 128 + w * 32 + i * 16 + quad * 4;
#pragma unroll
      for (int r = 0; r < 4; ++r) {
#pragma unroll
        for (int j = 0; j < 2; ++j) {
          float v = sacc[i][j][r] * csc;
          if (diag && kb * 32 + j * 16 + l16 > qrow + r) v = -__builtin_inff();
          p[i][j][r] = v;
          need |= (v > thr[i][r]);
        }
      }
    }

    if (__builtin_expect(__any((int)need), 0)) {
      // heavy path: some row's max grew past m_i+THR -> full online-softmax step
#pragma unroll
      for (int i = 0; i < 2; ++i) {
#pragma unroll
        for (int r = 0; r < 4; ++r) {
          float mx = fmaxf(p[i][0][r], p[i][1][r]);
          mx = row_max16(mx);
          const float mnew = fmaxf(m_i[i][r], mx);
          const float alpha = __builtin_amdgcn_exp2f(m_i[i][r] - mnew);
          m_i[i][r] = mnew;
          thr[i][r] = mnew + THR;
          float s0 = 0.f;
#pragma unroll
          for (int j = 0; j < 2; ++j) {
            const float e = __builtin_amdgcn_exp2f(p[i][j][r] - mnew);
            p[i][j][r] = e;
            s0 += e;
          }
          lp[i][r] = lp[i][r] * alpha + s0;
#pragma unroll
          for (int s = 0; s < 8; ++s) o[i][s][r] *= alpha;
        }
      }
    } else {
      // light path (common): exp against stale max, no reductions, no rescale
#pragma unroll
      for (int i = 0; i < 2; ++i) {
#pragma unroll
        for (int r = 0; r < 4; ++r) {
          const float m = m_i[i][r];
          float s0 = 0.f;
#pragma unroll
          for (int j = 0; j < 2; ++j) {
            const float e = __builtin_amdgcn_exp2f(p[i][j][r] - m);
            p[i][j][r] = e;
            s0 += e;
          }
          lp[i][r] += s0;
        }
      }
    }

    // P: C-layout regs -> LDS (pad 40, 16B-aligned rows) -> A-layout frags
#pragma unroll
    for (int i = 0; i < 2; ++i)
#pragma unroll
      for (int j = 0; j < 2; ++j)
#pragma unroll
        for (int r = 0; r < 4; ++r)
          sP[w * 1280 + (i * 16 + quad * 4 + r) * 40 + j * 16 + l16] = __float2bfloat16(p[i][j][r]);

    // O += P(32x32) @ V(32x128): single K-step (BKV=32)
    const bf16x8 ap0 = *(const bf16x8*)&sP[w * 1280 + l16 * 40 + quad * 8];
    const bf16x8 ap1 = *(const bf16x8*)&sP[w * 1280 + (16 + l16) * 40 + quad * 8];
    const int chv = (quad ^ (l16 & 3)) << 3;
    __builtin_amdgcn_s_setprio(1);
#pragma unroll
    for (int s = 0; s < 8; ++s) {
      const bf16x8 bv = *(const bf16x8*)&sV[(s * 16 + l16) * 32 + chv];
      o[0][s] = MFMA_16x16x32(ap0, bv, o[0][s]);
      o[1][s] = MFMA_16x16x32(ap1, bv, o[1][s]);
    }
    __builtin_amdgcn_s_setprio(0);
  }

  // epilogue: row-reduce the lazy denominator, O /= l, write bf16
#pragma unroll
  for (int i = 0; i < 2; ++i) {
    float rl[4];
#pragma unroll
    for (int r = 0; r < 4; ++r) rl[r] = 1.f / row_sum16(lp[i][r]);
    bf16* dst = outb + (size_t)(b * 2048 + qb * 128 + w * 32 + i * 16) * 2048 + h * 128;
#pragma unroll
    for (int s = 0; s < 8; ++s)
#pragma unroll
      for (int r = 0; r < 4; ++r)
        dst[(size_t)(quad * 4 + r) * 2048 + s * 16 + l16] = __float2bfloat16(o[i][s][r] * rl[r]);
  }
}

// ---------------------------------------------------------------------------
extern "C" void kernel_launch(void* const* d_in, const int* in_sizes, int n_in,
                              void* d_out, int out_size, void* d_ws, size_t ws_size,
                              hipStream_t stream)
{
  (void)in_sizes; (void)n_in; (void)out_size; (void)ws_size;
  const float* x  = (const float*)d_in[0];   // [4,2048,2048]
  const float* Wa = (const float*)d_in[1];   // [6144,2048]
  const float* Wp = (const float*)d_in[2];   // [2048,2048]
  float* out = (float*)d_out;                // [4,2048,2048] fp32
  char* ws = (char*)d_ws;

  bf16* xb   = (bf16*)(ws + 0);              //  33,554,432  x bf16 (dead after GEMM1)
  bf16* Wab  = (bf16*)(ws + 33554432ull);    //  25,165,824  W_attn bf16
  bf16* Wpb  = (bf16*)(ws + 58720256ull);    //   8,388,608  W_proj bf16
  bf16* qkv  = (bf16*)(ws + 67108864ull);    // 100,663,296  [8192,6144] bf16
  bf16* attb = (bf16*)(ws + 167772160ull);   //  33,554,432  attn out bf16
  bf16* Vt   = xb;                           // alias: V transposed [64][128][2048]

  f32_to_bf16_k<<<8192, 256, 0, stream>>>(x,  xb,  4 * 2048 * 2048);
  f32_to_bf16_k<<<6144, 256, 0, stream>>>(Wa, Wab, 3 * 2048 * 2048);
  f32_to_bf16_k<<<2048, 256, 0, stream>>>(Wp, Wpb, 2048 * 2048);

  // qkv = x @ W_attn^T   [8192,6144]
  gemm_bt<<<dim3(48, 64), 256, 0, stream>>>(xb, Wab, qkv, nullptr, 8192, 6144, 2048);
  // Vt[bh][d][t]
  transpose_v<<<dim3(32, 64), 256, 0, stream>>>(qkv, Vt);
  // attention: BQ=128 -> 16 q-tiles
  flash_attn<<<dim3(16, 64), 256, 0, stream>>>(qkv, Vt, attb);
  // out = attb @ W_proj^T  [8192,2048] fp32
  gemm_bt<<<dim3(16, 64), 256, 0, stream>>>(attb, Wpb, nullptr, out, 8192, 2048, 2048);
}

// Round 2
// 640.099 us; speedup vs baseline: 1.2442x; 1.2442x over previous
//
#include <hip/hip_runtime.h>
#include <hip/hip_bf16.h>
#include <stdint.h>

typedef __hip_bfloat16 bf16;
typedef __attribute__((ext_vector_type(8))) __bf16 bf16x8;
typedef __attribute__((ext_vector_type(8))) unsigned short ushort8;
typedef __attribute__((ext_vector_type(4))) float floatx4;

#define MFMA_16x16x32(a, b, c) __builtin_amdgcn_mfma_f32_16x16x32_bf16((a), (b), (c), 0, 0, 0)

// async global->LDS, 16B per lane. LDS dest = wave-uniform base + lane*16.
__device__ __forceinline__ void async_load16(const bf16* g, bf16* l) {
  __builtin_amdgcn_global_load_lds(
      (const __attribute__((address_space(1))) unsigned int*)g,
      (__attribute__((address_space(3))) unsigned int*)l,
      16, 0, 0);
}

// DPP cross-lane (VALU pipe, not LDS): 16-lane row reductions
template <int CTRL>
__device__ __forceinline__ float dpp_f(float x) {
  return __builtin_bit_cast(float, __builtin_amdgcn_update_dpp(
      0, __builtin_bit_cast(int, x), CTRL, 0xf, 0xf, true));
}
__device__ __forceinline__ float row_max16(float x) {
  x = fmaxf(x, dpp_f<0xB1>(x));   // quad_perm(1,0,3,2)
  x = fmaxf(x, dpp_f<0x4E>(x));   // quad_perm(2,3,0,1)
  x = fmaxf(x, dpp_f<0x124>(x));  // row_ror:4
  x = fmaxf(x, dpp_f<0x128>(x));  // row_ror:8
  return x;
}
__device__ __forceinline__ float row_sum16(float x) {
  x += dpp_f<0xB1>(x);
  x += dpp_f<0x4E>(x);
  x += dpp_f<0x124>(x);
  x += dpp_f<0x128>(x);
  return x;
}

// ---------------------------------------------------------------------------
// fp32 -> bf16 cast, 8 elems/thread
// ---------------------------------------------------------------------------
__global__ __launch_bounds__(256)
void f32_to_bf16_k(const float* __restrict__ in, bf16* __restrict__ out, int n)
{
  const int i = (blockIdx.x * 256 + threadIdx.x) * 8;
  if (i >= n) return;
  bf16 tmp[8];
#pragma unroll
  for (int j = 0; j < 8; ++j) tmp[j] = __float2bfloat16(in[i + j]);
  *(ushort8*)&out[i] = *(const ushort8*)tmp;
}

// ---------------------------------------------------------------------------
// C[M,N] = A[M,K] @ B[N,K]^T  — m97 tile + XOR swizzle + issue-after-barrier
// double-buffer: at __syncthreads the outstanding loads are one full compute
// phase old, so the vmcnt(0) drain is free. One barrier per K-step.
// ---------------------------------------------------------------------------
__global__ __launch_bounds__(256, 2)
void gemm_bt(const bf16* __restrict__ A, const bf16* __restrict__ B,
             bf16* __restrict__ Cb, float* __restrict__ Cf,
             int M, int N, int K)
{
  __shared__ __align__(16) bf16 sA[2][128 * 32];
  __shared__ __align__(16) bf16 sB[2][128 * 32];

  const int tid  = threadIdx.x;
  const int lane = tid & 63;
  const int w    = tid >> 6;
  const int wm   = w >> 1;
  const int wn   = w & 1;
  const int quad = lane >> 4;
  const int l16  = lane & 15;
  const int tileM = blockIdx.y * 128;
  const int tileN = blockIdx.x * 128;
  const int rmask = (l16 & 3) ^ ((l16 >> 2) & 3);

  floatx4 acc[4][4];
#pragma unroll
  for (int i = 0; i < 4; ++i)
#pragma unroll
    for (int j = 0; j < 4; ++j) acc[i][j] = (floatx4){0.f, 0.f, 0.f, 0.f};

  int st_row[2], st_col[2];
#pragma unroll
  for (int s = 0; s < 2; ++s) {
    const int cid = (w * 2 + s) * 64 + lane;
    const int row = cid >> 2;
    st_row[s] = row;
    st_col[s] = ((cid & 3) ^ ((row & 3) ^ ((row >> 2) & 3))) << 3;
  }

  // prologue: stage k0=0 into buf 0
#pragma unroll
  for (int s = 0; s < 2; ++s) {
    async_load16(A + (size_t)(tileM + st_row[s]) * K + st_col[s], &sA[0][(w * 2 + s) * 512]);
    async_load16(B + (size_t)(tileN + st_row[s]) * K + st_col[s], &sB[0][(w * 2 + s) * 512]);
  }

  int p = 0;
  for (int k0 = 0; k0 < K; k0 += 32, p ^= 1) {
    __syncthreads();  // drains loads(k0) (issued last iter) — latency hidden
    if (k0 + 32 < K) {
#pragma unroll
      for (int s = 0; s < 2; ++s) {
        async_load16(A + (size_t)(tileM + st_row[s]) * K + (k0 + 32) + st_col[s], &sA[p ^ 1][(w * 2 + s) * 512]);
        async_load16(B + (size_t)(tileN + st_row[s]) * K + (k0 + 32) + st_col[s], &sB[p ^ 1][(w * 2 + s) * 512]);
      }
    }

    bf16x8 af[4], bfr[4];
#pragma unroll
    for (int i = 0; i < 4; ++i)
      af[i] = *(const bf16x8*)&sA[p][(wm * 64 + i * 16 + l16) * 32 + (quad ^ rmask) * 8];
#pragma unroll
    for (int j = 0; j < 4; ++j)
      bfr[j] = *(const bf16x8*)&sB[p][(wn * 64 + j * 16 + l16) * 32 + (quad ^ rmask) * 8];
#pragma unroll
    for (int i = 0; i < 4; ++i)
#pragma unroll
      for (int j = 0; j < 4; ++j)
        acc[i][j] = MFMA_16x16x32(af[i], bfr[j], acc[i][j]);
  }

#pragma unroll
  for (int i = 0; i < 4; ++i)
#pragma unroll
    for (int j = 0; j < 4; ++j)
#pragma unroll
      for (int r = 0; r < 4; ++r) {
        const int row = tileM + wm * 64 + i * 16 + quad * 4 + r;
        const int col = tileN + wn * 64 + j * 16 + l16;
        if (Cf) Cf[(size_t)row * N + col] = acc[i][j][r];
        else    Cb[(size_t)row * N + col] = __float2bfloat16(acc[i][j][r]);
      }
}

// ---------------------------------------------------------------------------
// V transpose: qkv[b*T+t, 4096 + h*128 + dim] -> Vt[(bh*128 + dim)*2048 + t]
// ---------------------------------------------------------------------------
__global__ __launch_bounds__(256)
void transpose_v(const bf16* __restrict__ qkv, bf16* __restrict__ Vt)
{
  __shared__ bf16 tile[64 * 128];
  const int t0 = blockIdx.x * 64;
  const int bh = blockIdx.y;
  const int b = bh >> 4;
  const int h = bh & 15;
  const int tid = threadIdx.x;
  const bf16* src = qkv + (size_t)(b * 2048 + t0) * 6144 + 4096 + h * 128;
#pragma unroll
  for (int s = 0; s < 4; ++s) {
    const int cid = s * 256 + tid;
    const int row = cid >> 4;
    const int col = (cid & 15) << 3;
    *(ushort8*)&tile[row * 128 + col] = *(const ushort8*)&src[(size_t)row * 6144 + col];
  }
  __syncthreads();
  const int dim = tid >> 1;
  const int tp  = (tid & 1) << 5;
  bf16 vals[32];
#pragma unroll
  for (int t = 0; t < 32; ++t) vals[t] = tile[(tp + t) * 128 + dim];
  bf16* dst = Vt + (size_t)(bh * 128 + dim) * 2048 + t0 + tp;
#pragma unroll
  for (int s = 0; s < 4; ++s) *(ushort8*)&dst[s * 8] = ((const ushort8*)vals)[s];
}

// ---------------------------------------------------------------------------
// Flash attention, causal. BQ=128, BKV=32, double-buffered K/V, pipelined.
// 4 waves; wave w owns q-rows w*32..w*32+31 (2 m-subtiles). Q in registers.
// Softmax reductions via DPP (VALU pipe). LDS 42KB -> 3 blocks/CU.
// GRID: x = bh (fast axis, 64), y = q-tile (slow axis, 16, heavy-first).
// Work per block is prop. to qb+1; with bh fast, a CU's resident blocks span
// qbs {q, q+4, q+8, q+12} -> near-uniform per-CU work (was: same-qb 16x skew).
// ---------------------------------------------------------------------------
__global__ __launch_bounds__(256, 2)
void flash_attn(const bf16* __restrict__ qkv, const bf16* __restrict__ Vt,
                bf16* __restrict__ outb)
{
  // buf p (8192 elems): sK [32 keys][128 d] at +0, sV [128 d][32 keys] at +4096
  // Q (128x128 = 16384 elems) staged once through both bufs. sP after.
  __shared__ __align__(16) bf16 smem[16384 + 4 * 32 * 40];
  bf16* sP = smem + 16384;

  const int qb  = gridDim.y - 1 - blockIdx.y;   // heavy tiles dispatch first
  const int bh  = blockIdx.x;
  const int b   = bh >> 4;
  const int h   = bh & 15;
  const int tid = threadIdx.x;
  const int lane = tid & 63;
  const int w    = tid >> 6;
  const int quad = lane >> 4;
  const int l16  = lane & 15;

  const size_t rs = 6144;
  const bf16* Qg = qkv + (size_t)(b * 2048 + qb * 128) * rs + h * 128;
  const bf16* Kg = qkv + (size_t)(b * 2048) * rs + 2048 + h * 128;
  const bf16* Vg = Vt + (size_t)bh * 128 * 2048;

  // ---- stage Q (128x128), swizzled 16-chunk rows ----
#pragma unroll
  for (int s = 0; s < 8; ++s) {
    const int cid = (w * 8 + s) * 64 + lane;
    const int row = cid >> 4;
    const int col = ((cid & 15) ^ (row & 15)) << 3;
    async_load16(Qg + (size_t)row * rs + col, &smem[(w * 8 + s) * 512]);
  }
  __syncthreads();

  bf16x8 qf[2][4];
#pragma unroll
  for (int i = 0; i < 2; ++i)
#pragma unroll
    for (int kc = 0; kc < 4; ++kc)
      qf[i][kc] = *(const bf16x8*)&smem[(w * 32 + i * 16 + l16) * 128 + (((kc * 4 + quad) ^ l16) << 3)];
  __syncthreads();  // all waves done reading Q before buf0 is overwritten

  // K/V staging index precompute (2 insts each per wave per tile)
  int kq_row[2], kq_col[2], vv_row[2], vv_col[2];
#pragma unroll
  for (int s = 0; s < 2; ++s) {
    const int cid = (w * 2 + s) * 64 + lane;
    kq_row[s] = cid >> 4;                               // 16 chunks per 128-d row
    kq_col[s] = ((cid & 15) ^ (kq_row[s] & 15)) << 3;
    vv_row[s] = cid >> 2;                               // 4 chunks per 32-key row
    vv_col[s] = ((cid & 3) ^ (vv_row[s] & 3)) << 3;
  }

  const int kb_end = 4 * qb + 4;
  // prologue: stage tile 0 into buf 0
#pragma unroll
  for (int s = 0; s < 2; ++s) {
    async_load16(Kg + (size_t)kq_row[s] * rs + kq_col[s],      &smem[(w * 2 + s) * 512]);
    async_load16(Vg + (size_t)vv_row[s] * 2048 + vv_col[s],    &smem[4096 + (w * 2 + s) * 512]);
  }

  floatx4 o[2][8];
#pragma unroll
  for (int i = 0; i < 2; ++i)
#pragma unroll
    for (int s = 0; s < 8; ++s) o[i][s] = (floatx4){0.f, 0.f, 0.f, 0.f};
  float m_i[2][4], l_i[2][4];
#pragma unroll
  for (int i = 0; i < 2; ++i)
#pragma unroll
    for (int r = 0; r < 4; ++r) { m_i[i][r] = -__builtin_inff(); l_i[i][r] = 0.f; }

  const float csc = 1.4426950408889634f * 0.08838834764831845f; // log2(e)/sqrt(128)

  for (int kb = 0; kb < kb_end; ++kb) {
    __syncthreads();  // drains loads(kb) (issued last iter) + protects bufs
    if (kb + 1 < kb_end) {
      bf16* nb = smem + ((kb + 1) & 1) * 8192;
#pragma unroll
      for (int s = 0; s < 2; ++s) {
        async_load16(Kg + (size_t)((kb + 1) * 32 + kq_row[s]) * rs + kq_col[s], nb + (w * 2 + s) * 512);
        async_load16(Vg + (size_t)vv_row[s] * 2048 + (kb + 1) * 32 + vv_col[s], nb + 4096 + (w * 2 + s) * 512);
      }
    }
    // wave-uniform skip: whole key tile above all of this wave's rows
    if (kb * 32 > qb * 128 + w * 32 + 31) continue;

    const bf16* sK = smem + (kb & 1) * 8192;
    const bf16* sV = sK + 4096;

    // S = Q_w(32x128) @ K^T(128x32)
    floatx4 sacc[2][2];
#pragma unroll
    for (int i = 0; i < 2; ++i)
#pragma unroll
      for (int j = 0; j < 2; ++j) sacc[i][j] = (floatx4){0.f, 0.f, 0.f, 0.f};
#pragma unroll
    for (int kc = 0; kc < 4; ++kc) {
      const int ch = ((kc * 4 + quad) ^ l16) << 3;
#pragma unroll
      for (int j = 0; j < 2; ++j) {
        const bf16x8 bk = *(const bf16x8*)&sK[(j * 16 + l16) * 128 + ch];
        sacc[0][j] = MFMA_16x16x32(qf[0][kc], bk, sacc[0][j]);
        sacc[1][j] = MFMA_16x16x32(qf[1][kc], bk, sacc[1][j]);
      }
    }

    // scale + causal mask + online softmax (row = 16 contiguous lanes)
    const bool diag = (kb * 32 + 31 > qb * 128 + w * 32);
    float p[2][2][4];
#pragma unroll
    for (int i = 0; i < 2; ++i) {
      const int qrow = qb * 128 + w * 32 + i * 16 + quad * 4;
#pragma unroll
      for (int r = 0; r < 4; ++r) {
        float mx = -__builtin_inff();
#pragma unroll
        for (int j = 0; j < 2; ++j) {
          float v = sacc[i][j][r] * csc;
          if (diag && kb * 32 + j * 16 + l16 > qrow + r) v = -__builtin_inff();
          p[i][j][r] = v;
          mx = fmaxf(mx, v);
        }
        mx = row_max16(mx);
        const float mnew = fmaxf(m_i[i][r], mx);
        const float alpha = __builtin_amdgcn_exp2f(m_i[i][r] - mnew);
        m_i[i][r] = mnew;
        float rsl = 0.f;
#pragma unroll
        for (int j = 0; j < 2; ++j) {
          const float e = __builtin_amdgcn_exp2f(p[i][j][r] - mnew);
          p[i][j][r] = e;
          rsl += e;
        }
        l_i[i][r] = alpha * l_i[i][r] + row_sum16(rsl);
#pragma unroll
        for (int s = 0; s < 8; ++s) o[i][s][r] *= alpha;
      }
    }

    // P: C-layout regs -> LDS (pad 40, 16B-aligned rows) -> A-layout frags
#pragma unroll
    for (int i = 0; i < 2; ++i)
#pragma unroll
      for (int j = 0; j < 2; ++j)
#pragma unroll
        for (int r = 0; r < 4; ++r)
          sP[w * 1280 + (i * 16 + quad * 4 + r) * 40 + j * 16 + l16] = __float2bfloat16(p[i][j][r]);

    // O += P(32x32) @ V(32x128): single K-step (BKV=32)
    const bf16x8 ap0 = *(const bf16x8*)&sP[w * 1280 + l16 * 40 + quad * 8];
    const bf16x8 ap1 = *(const bf16x8*)&sP[w * 1280 + (16 + l16) * 40 + quad * 8];
    const int chv = (quad ^ (l16 & 3)) << 3;
#pragma unroll
    for (int s = 0; s < 8; ++s) {
      const bf16x8 bv = *(const bf16x8*)&sV[(s * 16 + l16) * 32 + chv];
      o[0][s] = MFMA_16x16x32(ap0, bv, o[0][s]);
      o[1][s] = MFMA_16x16x32(ap1, bv, o[1][s]);
    }
  }

  // epilogue: O /= l, write bf16
#pragma unroll
  for (int i = 0; i < 2; ++i) {
    float rl[4];
#pragma unroll
    for (int r = 0; r < 4; ++r) rl[r] = 1.f / l_i[i][r];
    bf16* dst = outb + (size_t)(b * 2048 + qb * 128 + w * 32 + i * 16) * 2048 + h * 128;
#pragma unroll
    for (int s = 0; s < 8; ++s)
#pragma unroll
      for (int r = 0; r < 4; ++r)
        dst[(size_t)(quad * 4 + r) * 2048 + s * 16 + l16] = __float2bfloat16(o[i][s][r] * rl[r]);
  }
}

// ---------------------------------------------------------------------------
extern "C" void kernel_launch(void* const* d_in, const int* in_sizes, int n_in,
                              void* d_out, int out_size, void* d_ws, size_t ws_size,
                              hipStream_t stream)
{
  (void)in_sizes; (void)n_in; (void)out_size; (void)ws_size;
  const float* x  = (const float*)d_in[0];   // [4,2048,2048]
  const float* Wa = (const float*)d_in[1];   // [6144,2048]
  const float* Wp = (const float*)d_in[2];   // [2048,2048]
  float* out = (float*)d_out;                // [4,2048,2048] fp32
  char* ws = (char*)d_ws;

  bf16* xb   = (bf16*)(ws + 0);              //  33,554,432  x bf16 (dead after GEMM1)
  bf16* Wab  = (bf16*)(ws + 33554432ull);    //  25,165,824  W_attn bf16
  bf16* Wpb  = (bf16*)(ws + 58720256ull);    //   8,388,608  W_proj bf16
  bf16* qkv  = (bf16*)(ws + 67108864ull);    // 100,663,296  [8192,6144] bf16
  bf16* attb = (bf16*)(ws + 167772160ull);   //  33,554,432  attn out bf16
  bf16* Vt   = xb;                           // alias: V transposed [64][128][2048]

  f32_to_bf16_k<<<8192, 256, 0, stream>>>(x,  xb,  4 * 2048 * 2048);
  f32_to_bf16_k<<<6144, 256, 0, stream>>>(Wa, Wab, 3 * 2048 * 2048);
  f32_to_bf16_k<<<2048, 256, 0, stream>>>(Wp, Wpb, 2048 * 2048);

  // qkv = x @ W_attn^T   [8192,6144]
  gemm_bt<<<dim3(48, 64), 256, 0, stream>>>(xb, Wab, qkv, nullptr, 8192, 6144, 2048);
  // Vt[bh][d][t]
  transpose_v<<<dim3(32, 64), 256, 0, stream>>>(qkv, Vt);
  // attention: x = bh (64), y = q-tile (16, heavy-first) for per-CU balance
  flash_attn<<<dim3(64, 16), 256, 0, stream>>>(qkv, Vt, attb);
  // out = attb @ W_proj^T  [8192,2048] fp32
  gemm_bt<<<dim3(16, 64), 256, 0, stream>>>(attb, Wpb, nullptr, out, 8192, 2048, 2048);
}

// Round 3
// 577.043 us; speedup vs baseline: 1.3802x; 1.1093x over previous
//
#include <hip/hip_runtime.h>
#include <hip/hip_bf16.h>
#include <stdint.h>

typedef __hip_bfloat16 bf16;
typedef __attribute__((ext_vector_type(8))) __bf16 bf16x8;
typedef __attribute__((ext_vector_type(8))) unsigned short ushort8;
typedef __attribute__((ext_vector_type(4))) float floatx4;

#define MFMA_16x16x32(a, b, c) __builtin_amdgcn_mfma_f32_16x16x32_bf16((a), (b), (c), 0, 0, 0)

// async global->LDS, 16B per lane. LDS dest = wave-uniform base + lane*16.
__device__ __forceinline__ void async_load16(const bf16* g, bf16* l) {
  __builtin_amdgcn_global_load_lds(
      (const __attribute__((address_space(1))) unsigned int*)g,
      (__attribute__((address_space(3))) unsigned int*)l,
      16, 0, 0);
}

// DPP cross-lane (VALU pipe, not LDS): 16-lane row reductions
template <int CTRL>
__device__ __forceinline__ float dpp_f(float x) {
  return __builtin_bit_cast(float, __builtin_amdgcn_update_dpp(
      0, __builtin_bit_cast(int, x), CTRL, 0xf, 0xf, true));
}
__device__ __forceinline__ float row_max16(float x) {
  x = fmaxf(x, dpp_f<0xB1>(x));   // quad_perm(1,0,3,2)
  x = fmaxf(x, dpp_f<0x4E>(x));   // quad_perm(2,3,0,1)
  x = fmaxf(x, dpp_f<0x124>(x));  // row_ror:4
  x = fmaxf(x, dpp_f<0x128>(x));  // row_ror:8
  return x;
}
__device__ __forceinline__ float row_sum16(float x) {
  x += dpp_f<0xB1>(x);
  x += dpp_f<0x4E>(x);
  x += dpp_f<0x124>(x);
  x += dpp_f<0x128>(x);
  return x;
}

// ---------------------------------------------------------------------------
// fp32 -> bf16 cast, 8 elems/thread
// ---------------------------------------------------------------------------
__global__ __launch_bounds__(256)
void f32_to_bf16_k(const float* __restrict__ in, bf16* __restrict__ out, int n)
{
  const int i = (blockIdx.x * 256 + threadIdx.x) * 8;
  if (i >= n) return;
  bf16 tmp[8];
#pragma unroll
  for (int j = 0; j < 8; ++j) tmp[j] = __float2bfloat16(in[i + j]);
  *(ushort8*)&out[i] = *(const ushort8*)tmp;
}

// ---------------------------------------------------------------------------
// C[M,N] = A[M,K] @ B[N,K]^T — 256x256 tile, BK=64, 8-phase schedule (T2+T3+
// T4+T5). 512 thr = 8 waves (2M x 4N); per-wave output 128x64 = acc[8][4].
// LDS 128KB: sA/sB double-buffered [256][64] bf16, (row&7)-XOR chunk swizzle
// (write side: pre-swizzled global source, gload_lds writes linear; read
// side: same XOR on ds_read chunk).
// Per K-tile: 4 phases, each {ds_read quadrant | stage 1 set | bar | 16 MFMA
// | bar}; ONE counted s_waitcnt vmcnt(4) per K-tile (phase 4) — two staging
// sets (tile t+2's A0,B0) remain in flight across the barrier.
// Staging order (steady state, tile t): P1:SB1(t+1)  P2:SA1(t+1)
//   P3:SA0(t+2)->cur buf (A0 region consumed end of P2)  P4:SB0(t+2).
// Wait coverage at t.P4: 4 newest outstanding = SA0/SB0(t+2); everything
// tile t+1 reads (SA0,SB0 @t-1.P3/P4; SB1 @t.P1; SA1 @t.P2) is older => landed.
// ---------------------------------------------------------------------------
#define G_BAR __builtin_amdgcn_s_barrier()

#define G_STAGE(pg, ls, tt, h)                                                  \
  do {                                                                          \
    async_load16((pg) + (size_t)((h) * 64) * K + (size_t)(tt) * 64,             \
                 (ls) + (h) * 4096 + lws);                                      \
    async_load16((pg) + (size_t)((h) * 64 + 128) * K + (size_t)(tt) * 64,       \
                 (ls) + (h) * 4096 + 8192 + lws);                               \
  } while (0)

#define G_RD_A(mh)                                                              \
  _Pragma("unroll") for (int i = 0; i < 4; ++i) {                               \
    const int rb = (wm * 128 + (mh) * 64 + i * 16 + l16) * 64;                  \
    af[i][0] = *(const bf16x8*)&sAd[rb + ach0];                                 \
    af[i][1] = *(const bf16x8*)&sAd[rb + ach1];                                 \
  }

#define G_RD_B(dst, nh)                                                         \
  _Pragma("unroll") for (int j = 0; j < 2; ++j) {                               \
    const int rb = (wn * 64 + (nh) * 32 + j * 16 + l16) * 64;                   \
    dst[j][0] = *(const bf16x8*)&sBd[rb + ach0];                                \
    dst[j][1] = *(const bf16x8*)&sBd[rb + ach1];                                \
  }

#define G_MM(mh, nh, BF)                                                        \
  __builtin_amdgcn_s_setprio(1);                                                \
  _Pragma("unroll") for (int kk = 0; kk < 2; ++kk)                              \
  _Pragma("unroll") for (int i = 0; i < 4; ++i)                                 \
  _Pragma("unroll") for (int j = 0; j < 2; ++j)                                 \
    acc[(mh) * 4 + i][(nh) * 2 + j] =                                           \
        MFMA_16x16x32(af[i][kk], BF[j][kk], acc[(mh) * 4 + i][(nh) * 2 + j]);   \
  __builtin_amdgcn_s_setprio(0);

__global__ __launch_bounds__(512, 2)
void gemm_bt(const bf16* __restrict__ A, const bf16* __restrict__ B,
             bf16* __restrict__ Cb, float* __restrict__ Cf,
             int M, int N, int K)
{
  __shared__ __align__(16) bf16 sA[2][256 * 64];
  __shared__ __align__(16) bf16 sB[2][256 * 64];

  const int tid  = threadIdx.x;
  const int lane = tid & 63;
  const int w    = tid >> 6;   // 0..7
  const int wm   = w >> 2;     // 0..1
  const int wn   = w & 3;      // 0..3
  const int quad = lane >> 4;
  const int l16  = lane & 15;

  // 1-D grid, bijective XCD swizzle (nwg % 8 == 0 for all our launches)
  const int nbx = N >> 8;
  const int nwg = nbx * (M >> 8);
  const int wg  = (blockIdx.x & 7) * (nwg >> 3) + (blockIdx.x >> 3);
  const int tileM = (wg / nbx) << 8;
  const int tileN = (wg % nbx) << 8;

  // staging geometry: thread cid=s*512+tid writes physical chunk (tid&7) of
  // row srow+h*64+s*128; source fetches logical chunk (tid&7)^(row&7).
  const int srow = tid >> 3;                          // 0..63
  const int scol = ((tid & 7) ^ (srow & 7)) << 3;     // pre-swizzled (elems)
  const bf16* pA = A + (size_t)(tileM + srow) * K + scol;
  const bf16* pB = B + (size_t)(tileN + srow) * K + scol;
  const int lws = w * 512;                            // wave lds base in a set

  // ds-read swizzled chunk offsets (elems): logical chunk kk*4+quad, row&7=l16&7
  const int ach0 = ((quad ^ (l16 & 7)) << 3);
  const int ach1 = (((4 + quad) ^ (l16 & 7)) << 3);

  floatx4 acc[8][4];
#pragma unroll
  for (int i = 0; i < 8; ++i)
#pragma unroll
    for (int j = 0; j < 4; ++j) acc[i][j] = (floatx4){0.f, 0.f, 0.f, 0.f};

  const int T = K >> 6;

  // ---- prologue: tile0 all 4 sets, then tile1 A0,B0 (issue order = wait order)
  G_STAGE(pA, &sA[0][0], 0, 0);
  G_STAGE(pB, &sB[0][0], 0, 0);
  G_STAGE(pB, &sB[0][0], 0, 1);
  G_STAGE(pA, &sA[0][0], 0, 1);
  if (T > 1) {
    G_STAGE(pA, &sA[1][0], 1, 0);
    G_STAGE(pB, &sB[1][0], 1, 0);
    asm volatile("s_waitcnt vmcnt(4)" ::: "memory");
  } else {
    asm volatile("s_waitcnt vmcnt(0)" ::: "memory");
  }
  G_BAR;

  bf16x8 af[4][2], bf0[2][2], bf1[2][2];
  for (int t = 0; t < T; ++t) {
    const bf16* sAd = &sA[t & 1][0];
    const bf16* sBd = &sB[t & 1][0];
    bf16* sAn = &sA[(t + 1) & 1][0];  // buffer of tile t+1
    bf16* sBn = &sB[(t + 1) & 1][0];
    bf16* sAc = &sA[t & 1][0];        // buffer of tile t+2 (current)
    bf16* sBc = &sB[t & 1][0];

    // P1: quadrant (mh0,nh0)
    G_RD_A(0); G_RD_B(bf0, 0);
    if (t + 1 < T) G_STAGE(pB, sBn, t + 1, 1);
    G_BAR; G_MM(0, 0, bf0); G_BAR;

    // P2: quadrant (mh0,nh1)
    G_RD_B(bf1, 1);
    if (t + 1 < T) G_STAGE(pA, sAn, t + 1, 1);
    G_BAR; G_MM(0, 1, bf1); G_BAR;

    // P3: quadrant (mh1,nh0) — A0 region of current buf consumed, re-stage it
    G_RD_A(1);
    if (t + 2 < T) G_STAGE(pA, sAc, t + 2, 0);
    G_BAR; G_MM(1, 0, bf0); G_BAR;

    // P4: quadrant (mh1,nh1) + the once-per-K-tile counted wait
    if (t + 2 < T) G_STAGE(pB, sBc, t + 2, 0);
    G_BAR; G_MM(1, 1, bf1);
    if (t + 2 < T) asm volatile("s_waitcnt vmcnt(4)" ::: "memory");
    else           asm volatile("s_waitcnt vmcnt(0)" ::: "memory");
    G_BAR;
  }

  // ---- epilogue
  const int orow = tileM + wm * 128 + quad * 4;
  const int ocol = tileN + wn * 64 + l16;
  if (Cf) {
#pragma unroll
    for (int fm = 0; fm < 8; ++fm)
#pragma unroll
      for (int fn = 0; fn < 4; ++fn)
#pragma unroll
        for (int r = 0; r < 4; ++r)
          Cf[(size_t)(orow + fm * 16 + r) * N + ocol + fn * 16] = acc[fm][fn][r];
  } else {
#pragma unroll
    for (int fm = 0; fm < 8; ++fm)
#pragma unroll
      for (int fn = 0; fn < 4; ++fn)
#pragma unroll
        for (int r = 0; r < 4; ++r)
          Cb[(size_t)(orow + fm * 16 + r) * N + ocol + fn * 16] =
              __float2bfloat16(acc[fm][fn][r]);
  }
}

// ---------------------------------------------------------------------------
// V transpose: qkv[b*T+t, 4096 + h*128 + dim] -> Vt[(bh*128 + dim)*2048 + t]
// ---------------------------------------------------------------------------
__global__ __launch_bounds__(256)
void transpose_v(const bf16* __restrict__ qkv, bf16* __restrict__ Vt)
{
  __shared__ bf16 tile[64 * 128];
  const int t0 = blockIdx.x * 64;
  const int bh = blockIdx.y;
  const int b = bh >> 4;
  const int h = bh & 15;
  const int tid = threadIdx.x;
  const bf16* src = qkv + (size_t)(b * 2048 + t0) * 6144 + 4096 + h * 128;
#pragma unroll
  for (int s = 0; s < 4; ++s) {
    const int cid = s * 256 + tid;
    const int row = cid >> 4;
    const int col = (cid & 15) << 3;
    *(ushort8*)&tile[row * 128 + col] = *(const ushort8*)&src[(size_t)row * 6144 + col];
  }
  __syncthreads();
  const int dim = tid >> 1;
  const int tp  = (tid & 1) << 5;
  bf16 vals[32];
#pragma unroll
  for (int t = 0; t < 32; ++t) vals[t] = tile[(tp + t) * 128 + dim];
  bf16* dst = Vt + (size_t)(bh * 128 + dim) * 2048 + t0 + tp;
#pragma unroll
  for (int s = 0; s < 4; ++s) *(ushort8*)&dst[s * 8] = ((const ushort8*)vals)[s];
}

// ---------------------------------------------------------------------------
// Flash attention, causal. BQ=128, BKV=32, double-buffered K/V, pipelined.
// 4 waves; wave w owns q-rows w*32..w*32+31 (2 m-subtiles). Q in registers.
// Softmax reductions via DPP (VALU pipe). LDS 42KB -> 3 blocks/CU.
// GRID: x = bh (fast axis, 64), y = q-tile (slow axis, 16, heavy-first).
// ---------------------------------------------------------------------------
__global__ __launch_bounds__(256, 2)
void flash_attn(const bf16* __restrict__ qkv, const bf16* __restrict__ Vt,
                bf16* __restrict__ outb)
{
  // buf p (8192 elems): sK [32 keys][128 d] at +0, sV [128 d][32 keys] at +4096
  // Q (128x128 = 16384 elems) staged once through both bufs. sP after.
  __shared__ __align__(16) bf16 smem[16384 + 4 * 32 * 40];
  bf16* sP = smem + 16384;

  const int qb  = gridDim.y - 1 - blockIdx.y;   // heavy tiles dispatch first
  const int bh  = blockIdx.x;
  const int b   = bh >> 4;
  const int h   = bh & 15;
  const int tid = threadIdx.x;
  const int lane = tid & 63;
  const int w    = tid >> 6;
  const int quad = lane >> 4;
  const int l16  = lane & 15;

  const size_t rs = 6144;
  const bf16* Qg = qkv + (size_t)(b * 2048 + qb * 128) * rs + h * 128;
  const bf16* Kg = qkv + (size_t)(b * 2048) * rs + 2048 + h * 128;
  const bf16* Vg = Vt + (size_t)bh * 128 * 2048;

  // ---- stage Q (128x128), swizzled 16-chunk rows ----
#pragma unroll
  for (int s = 0; s < 8; ++s) {
    const int cid = (w * 8 + s) * 64 + lane;
    const int row = cid >> 4;
    const int col = ((cid & 15) ^ (row & 15)) << 3;
    async_load16(Qg + (size_t)row * rs + col, &smem[(w * 8 + s) * 512]);
  }
  __syncthreads();

  bf16x8 qf[2][4];
#pragma unroll
  for (int i = 0; i < 2; ++i)
#pragma unroll
    for (int kc = 0; kc < 4; ++kc)
      qf[i][kc] = *(const bf16x8*)&smem[(w * 32 + i * 16 + l16) * 128 + (((kc * 4 + quad) ^ l16) << 3)];
  __syncthreads();  // all waves done reading Q before buf0 is overwritten

  // K/V staging index precompute (2 insts each per wave per tile)
  int kq_row[2], kq_col[2], vv_row[2], vv_col[2];
#pragma unroll
  for (int s = 0; s < 2; ++s) {
    const int cid = (w * 2 + s) * 64 + lane;
    kq_row[s] = cid >> 4;                               // 16 chunks per 128-d row
    kq_col[s] = ((cid & 15) ^ (kq_row[s] & 15)) << 3;
    vv_row[s] = cid >> 2;                               // 4 chunks per 32-key row
    vv_col[s] = ((cid & 3) ^ (vv_row[s] & 3)) << 3;
  }

  const int kb_end = 4 * qb + 4;
  // prologue: stage tile 0 into buf 0
#pragma unroll
  for (int s = 0; s < 2; ++s) {
    async_load16(Kg + (size_t)kq_row[s] * rs + kq_col[s],      &smem[(w * 2 + s) * 512]);
    async_load16(Vg + (size_t)vv_row[s] * 2048 + vv_col[s],    &smem[4096 + (w * 2 + s) * 512]);
  }

  floatx4 o[2][8];
#pragma unroll
  for (int i = 0; i < 2; ++i)
#pragma unroll
    for (int s = 0; s < 8; ++s) o[i][s] = (floatx4){0.f, 0.f, 0.f, 0.f};
  float m_i[2][4], l_i[2][4];
#pragma unroll
  for (int i = 0; i < 2; ++i)
#pragma unroll
    for (int r = 0; r < 4; ++r) { m_i[i][r] = -__builtin_inff(); l_i[i][r] = 0.f; }

  const float csc = 1.4426950408889634f * 0.08838834764831845f; // log2(e)/sqrt(128)

  for (int kb = 0; kb < kb_end; ++kb) {
    __syncthreads();  // drains loads(kb) (issued last iter) + protects bufs
    if (kb + 1 < kb_end) {
      bf16* nb = smem + ((kb + 1) & 1) * 8192;
#pragma unroll
      for (int s = 0; s < 2; ++s) {
        async_load16(Kg + (size_t)((kb + 1) * 32 + kq_row[s]) * rs + kq_col[s], nb + (w * 2 + s) * 512);
        async_load16(Vg + (size_t)vv_row[s] * 2048 + (kb + 1) * 32 + vv_col[s], nb + 4096 + (w * 2 + s) * 512);
      }
    }
    // wave-uniform skip: whole key tile above all of this wave's rows
    if (kb * 32 > qb * 128 + w * 32 + 31) continue;

    const bf16* sK = smem + (kb & 1) * 8192;
    const bf16* sV = sK + 4096;

    // S = Q_w(32x128) @ K^T(128x32)
    floatx4 sacc[2][2];
#pragma unroll
    for (int i = 0; i < 2; ++i)
#pragma unroll
      for (int j = 0; j < 2; ++j) sacc[i][j] = (floatx4){0.f, 0.f, 0.f, 0.f};
#pragma unroll
    for (int kc = 0; kc < 4; ++kc) {
      const int ch = ((kc * 4 + quad) ^ l16) << 3;
#pragma unroll
      for (int j = 0; j < 2; ++j) {
        const bf16x8 bk = *(const bf16x8*)&sK[(j * 16 + l16) * 128 + ch];
        sacc[0][j] = MFMA_16x16x32(qf[0][kc], bk, sacc[0][j]);
        sacc[1][j] = MFMA_16x16x32(qf[1][kc], bk, sacc[1][j]);
      }
    }

    // scale + causal mask + online softmax (row = 16 contiguous lanes)
    const bool diag = (kb * 32 + 31 > qb * 128 + w * 32);
    float p[2][2][4];
#pragma unroll
    for (int i = 0; i < 2; ++i) {
      const int qrow = qb * 128 + w * 32 + i * 16 + quad * 4;
#pragma unroll
      for (int r = 0; r < 4; ++r) {
        float mx = -__builtin_inff();
#pragma unroll
        for (int j = 0; j < 2; ++j) {
          float v = sacc[i][j][r] * csc;
          if (diag && kb * 32 + j * 16 + l16 > qrow + r) v = -__builtin_inff();
          p[i][j][r] = v;
          mx = fmaxf(mx, v);
        }
        mx = row_max16(mx);
        const float mnew = fmaxf(m_i[i][r], mx);
        const float alpha = __builtin_amdgcn_exp2f(m_i[i][r] - mnew);
        m_i[i][r] = mnew;
        float rsl = 0.f;
#pragma unroll
        for (int j = 0; j < 2; ++j) {
          const float e = __builtin_amdgcn_exp2f(p[i][j][r] - mnew);
          p[i][j][r] = e;
          rsl += e;
        }
        l_i[i][r] = alpha * l_i[i][r] + row_sum16(rsl);
#pragma unroll
        for (int s = 0; s < 8; ++s) o[i][s][r] *= alpha;
      }
    }

    // P: C-layout regs -> LDS (pad 40, 16B-aligned rows) -> A-layout frags
#pragma unroll
    for (int i = 0; i < 2; ++i)
#pragma unroll
      for (int j = 0; j < 2; ++j)
#pragma unroll
        for (int r = 0; r < 4; ++r)
          sP[w * 1280 + (i * 16 + quad * 4 + r) * 40 + j * 16 + l16] = __float2bfloat16(p[i][j][r]);

    // O += P(32x32) @ V(32x128): single K-step (BKV=32)
    const bf16x8 ap0 = *(const bf16x8*)&sP[w * 1280 + l16 * 40 + quad * 8];
    const bf16x8 ap1 = *(const bf16x8*)&sP[w * 1280 + (16 + l16) * 40 + quad * 8];
    const int chv = (quad ^ (l16 & 3)) << 3;
#pragma unroll
    for (int s = 0; s < 8; ++s) {
      const bf16x8 bv = *(const bf16x8*)&sV[(s * 16 + l16) * 32 + chv];
      o[0][s] = MFMA_16x16x32(ap0, bv, o[0][s]);
      o[1][s] = MFMA_16x16x32(ap1, bv, o[1][s]);
    }
  }

  // epilogue: O /= l, write bf16
#pragma unroll
  for (int i = 0; i < 2; ++i) {
    float rl[4];
#pragma unroll
    for (int r = 0; r < 4; ++r) rl[r] = 1.f / l_i[i][r];
    bf16* dst = outb + (size_t)(b * 2048 + qb * 128 + w * 32 + i * 16) * 2048 + h * 128;
#pragma unroll
    for (int s = 0; s < 8; ++s)
#pragma unroll
      for (int r = 0; r < 4; ++r)
        dst[(size_t)(quad * 4 + r) * 2048 + s * 16 + l16] = __float2bfloat16(o[i][s][r] * rl[r]);
  }
}

// ---------------------------------------------------------------------------
extern "C" void kernel_launch(void* const* d_in, const int* in_sizes, int n_in,
                              void* d_out, int out_size, void* d_ws, size_t ws_size,
                              hipStream_t stream)
{
  (void)in_sizes; (void)n_in; (void)out_size; (void)ws_size;
  const float* x  = (const float*)d_in[0];   // [4,2048,2048]
  const float* Wa = (const float*)d_in[1];   // [6144,2048]
  const float* Wp = (const float*)d_in[2];   // [2048,2048]
  float* out = (float*)d_out;                // [4,2048,2048] fp32
  char* ws = (char*)d_ws;

  bf16* xb   = (bf16*)(ws + 0);              //  33,554,432  x bf16 (dead after GEMM1)
  bf16* Wab  = (bf16*)(ws + 33554432ull);    //  25,165,824  W_attn bf16
  bf16* Wpb  = (bf16*)(ws + 58720256ull);    //   8,388,608  W_proj bf16
  bf16* qkv  = (bf16*)(ws + 67108864ull);    // 100,663,296  [8192,6144] bf16
  bf16* attb = (bf16*)(ws + 167772160ull);   //  33,554,432  attn out bf16
  bf16* Vt   = xb;                           // alias: V transposed [64][128][2048]

  f32_to_bf16_k<<<8192, 256, 0, stream>>>(x,  xb,  4 * 2048 * 2048);
  f32_to_bf16_k<<<6144, 256, 0, stream>>>(Wa, Wab, 3 * 2048 * 2048);
  f32_to_bf16_k<<<2048, 256, 0, stream>>>(Wp, Wpb, 2048 * 2048);

  // qkv = x @ W_attn^T   [8192,6144]; 256x256 tiles -> 24x32 = 768 wgs
  gemm_bt<<<dim3(768), 512, 0, stream>>>(xb, Wab, qkv, nullptr, 8192, 6144, 2048);
  // Vt[bh][d][t]
  transpose_v<<<dim3(32, 64), 256, 0, stream>>>(qkv, Vt);
  // attention: x = bh (64), y = q-tile (16, heavy-first) for per-CU balance
  flash_attn<<<dim3(64, 16), 256, 0, stream>>>(qkv, Vt, attb);
  // out = attb @ W_proj^T  [8192,2048] fp32; 8x32 = 256 wgs
  gemm_bt<<<dim3(256), 512, 0, stream>>>(attb, Wpb, nullptr, out, 8192, 2048, 2048);
}